// Round 14
// baseline (1572.278 us; speedup 1.0000x reference)
//
#include <hip/hip_runtime.h>
#include <stdint.h>

#define EPS 1e-5f

typedef __attribute__((ext_vector_type(8))) __bf16 bf16x8;
typedef __attribute__((ext_vector_type(16))) float f32x16;
typedef __attribute__((ext_vector_type(4))) float f32x4;

__device__ __forceinline__ int swz4(int r) { return (r ^ (r >> 2)) & 3; }

__device__ __forceinline__ unsigned short f2bf(float f) {
  union { float f; unsigned u; } v; v.f = f;
  unsigned r = v.u + 0x7fffu + ((v.u >> 16) & 1u);
  return (unsigned short)(r >> 16);
}

__device__ __forceinline__ void glds16(const unsigned short* g, unsigned short* l) {
  __builtin_amdgcn_global_load_lds(
      (const __attribute__((address_space(1))) void*)g,
      (__attribute__((address_space(3))) void*)l, 16, 0, 0);
}
__device__ __forceinline__ void glds4(const unsigned short* g, unsigned short* l) {
  __builtin_amdgcn_global_load_lds(
      (const __attribute__((address_space(1))) void*)g,
      (__attribute__((address_space(3))) void*)l, 4, 0, 0);
}

template <int N>
__device__ __forceinline__ void vmwait() {
  asm volatile("s_waitcnt vmcnt(%0)" ::"n"(N) : "memory");
}

// ---------------------------------------------------------------------------
// Pack W [c2][c1][13][13] f32 -> bf16 per-K-step tiles = exact linear LDS
// image of the A tile (chunk swizzle baked in).
// K order: k = ((kh*8 + c1c)*13 + kw)*32 + c1i
// ---------------------------------------------------------------------------
__global__ __launch_bounds__(256) void pack_w_kernel(
    const float* __restrict__ W, unsigned short* __restrict__ Wp) {
  const int blk = blockIdx.x;  // c2*13 + kh
  const int c2 = blk / 13, kh = blk - c2 * 13;
  const int c1 = threadIdx.x;
  const int c2t = c2 >> 7, m = c2 & 127;
  const int c1c = c1 >> 5, c1i = c1 & 31;
  const float* src = W + (((size_t)(c2 * 256 + c1)) * 13 + kh) * 13;
  const int rowoff = (((c1i >> 3) ^ swz4(m)) << 3) + (c1i & 7);
#pragma unroll
  for (int kw = 0; kw < 13; ++kw) {
    const int ks = (kh * 8 + c1c) * 13 + kw;
    const size_t dst = (((size_t)c2t * 1352 + ks) * 128 + m) * 32 + rowoff;
    Wp[dst] = f2bf(src[kw]);
  }
}

// ---------------------------------------------------------------------------
// Pack x [b][c1][64][64] f32 -> xT[b][c1c][rowp 76][colp 80][c1i 32] bf16,
// zero-padded halo (rowp = row+6, colp = ic+8), chunk swizzle baked in.
// ---------------------------------------------------------------------------
__global__ __launch_bounds__(256) void pack_xt_kernel(
    const float* __restrict__ x, unsigned short* __restrict__ xT) {
  const int blk = blockIdx.x;  // (b*8 + c1c)*76 + rowp ; 4864 blocks
  const int rowp = blk % 76;
  const int bc = blk / 76;
  const int c1c = bc & 7, b = bc >> 3;
  const int row = rowp - 6;
  const bool rok = (unsigned)row < 64u;
  unsigned short* dst = xT + (size_t)blk * 2560;
  const float* srcb = x + (size_t)(b * 256 + c1c * 32) * 4096 +
                      (rok ? row * 64 : 0);
#pragma unroll
  for (int e = 0; e < 10; ++e) {
    const int idx = e * 256 + threadIdx.x;  // 0..2559
    const int colp = idx >> 5, c1i = idx & 31;
    const int ic = colp - 8;
    const float v = (rok && (unsigned)ic < 64u) ? srcb[(size_t)c1i * 4096 + ic] : 0.f;
    dst[colp * 32 + ((((c1i >> 3) ^ swz4(colp)) << 3)) + (c1i & 7)] = f2bf(v);
  }
}

// ---------------------------------------------------------------------------
// K-split implicit-GEMM conv -> f32 partials (plain disjoint stores).
// Block: 512 thr (8 waves 2M x 4N), tile 128 c2 x 256 sp (4h x 64w).
// Wave tile 64x64 via 32x32x16 MFMA. Grid 512 = 2 kHalf x 2 c2t x 8 b x 16 hq
// -> 2 independent blocks/CU, 4 waves/SIMD. 338 phases/block.
// W window staging (FIXED R14): 4 rounds/tile = 2 glds16 (4096 ush each) +
// 2 glds4 (1024 ush each) = 10240 ush exactly.
// ---------------------------------------------------------------------------
__global__ __launch_bounds__(512, 4) void conv14_kernel(
    const unsigned short* __restrict__ Wp, const unsigned short* __restrict__ xT,
    float* __restrict__ Ppart) {
  __shared__ __align__(16) unsigned short Abuf[2][8192];   // 2 x 16 KiB
  __shared__ __align__(16) unsigned short Wbuf[2][10240];  // 2 x 20 KiB (4 rows)

  const int tid = threadIdx.x;
  const int bid = blockIdx.x;
  const int b = bid & 7;  // XCD-aware: blocks on XCD k share batch image k
  const int hq = (bid >> 3) & 15;
  const int c2t = (bid >> 7) & 1;
  const int kHalf = bid >> 8;
  const int h0 = hq * 4;

  const int wid = tid >> 6, lane = tid & 63;
  const int wr = wid >> 2, wn = wid & 3;  // 2M x 4N wave grid
  const int l31 = lane & 31, hi2 = lane >> 5;

  int aoffs[2][2];  // byte offsets within one 8 KiB A step-tile
#pragma unroll
  for (int mt = 0; mt < 2; ++mt)
#pragma unroll
    for (int ks = 0; ks < 2; ++ks) {
      const int m = wr * 64 + mt * 32 + l31;
      aoffs[mt][ks] = m * 64 + (((ks * 2 + hi2) ^ swz4(m)) << 4);
    }
  int ndh[2], nwl[2];
#pragma unroll
  for (int nt = 0; nt < 2; ++nt) {
    const int n = wn * 64 + nt * 32 + l31;  // 0..255
    ndh[nt] = n >> 6;                       // 0..3 (4 rows)
    nwl[nt] = n & 63;
  }

  const int tid8 = tid * 8, tid2 = tid * 2;
  const int widA = wid * 512;   // glds16: 8 waves x 512 ush = 4096 ush/round
  const int wid128 = wid * 128; // glds4: 8 waves x 128 ush = 1024 ush/round

  const size_t c2base = (size_t)c2t * 1352;
  const int kBaseStep = kHalf * 676;
  const int kBaseTile = kHalf * 52;
  const int bc8 = b * 8;
  const char* Abase = (const char*)&Abuf[0][0];
  unsigned short* AbaseU = &Abuf[0][0];

  auto wtile = [&](int Tloc) -> const unsigned short* {  // Tloc 0..51
    const int T = kBaseTile + Tloc;
    const int kh = T >> 3, c1c = T & 7;
    return xT + (size_t)((bc8 + c1c) * 76 + h0 + kh) * 2560;  // 4 rows = 10240 ush
  };

  f32x16 acc[2][2];
#pragma unroll
  for (int i = 0; i < 2; ++i)
#pragma unroll
    for (int j = 0; j < 2; ++j)
#pragma unroll
      for (int r = 0; r < 16; ++r) acc[i][j][r] = 0.f;

  // cross-phase register double-buffer
  bf16x8 rE_A[2][2][2], rE_B[2][2][2], rO_A[2][2][2], rO_B[2][2][2];

  // A buffers: write target aWr (data for phase p+2), S1 reads aRd (p+1 data)
  int aWr = 0, aRd = 16384;  // byte offsets

  // ---- prologue
  {
    const unsigned short* ws = wtile(0);
    glds16(ws + tid8, &Wbuf[0][0] + widA);
    glds16(ws + 4096 + tid8, &Wbuf[0][4096] + widA);
    glds4(ws + 8192 + tid2, &Wbuf[0][8192] + wid128);
    glds4(ws + 9216 + tid2, &Wbuf[0][9216] + wid128);
    // A steps 0,1 -> buf0 ; steps 2,3 -> buf1
#pragma unroll
    for (int s = 0; s < 4; ++s) {
      const unsigned short* at =
          Wp + ((c2base + (size_t)(kBaseStep + s)) << 12);
      glds16(at + tid8, AbaseU + s * 4096 + widA);
    }
    vmwait<0>();
    __builtin_amdgcn_s_barrier();
    // preload phase-0 regs (steps 0,1 from buf0; W par0 cols kw 0,1)
    const char* abA = Abase;
    const char* abB = Abase + 8192;
    const char* wb0 = (const char*)&Wbuf[0][0];
#pragma unroll
    for (int ks = 0; ks < 2; ++ks) {
      rE_A[0][ks][0] = *(const bf16x8*)(abA + aoffs[0][ks]);
      rE_A[0][ks][1] = *(const bf16x8*)(abA + aoffs[1][ks]);
      rE_A[1][ks][0] = *(const bf16x8*)(abB + aoffs[0][ks]);
      rE_A[1][ks][1] = *(const bf16x8*)(abB + aoffs[1][ks]);
#pragma unroll
      for (int nt = 0; nt < 2; ++nt) {
        const int cA = nwl[nt] + 0 + 2;
        rE_B[0][ks][nt] = *(const bf16x8*)(wb0 + (ndh[nt] * 80 + cA) * 64 +
                                           (((ks * 2 + hi2) ^ swz4(cA)) << 4));
        const int cB = nwl[nt] + 1 + 2;
        rE_B[1][ks][nt] = *(const bf16x8*)(wb0 + (ndh[nt] * 80 + cB) * 64 +
                                           (((ks * 2 + hi2) ^ swz4(cB)) << 4));
      }
    }
    asm volatile("s_waitcnt lgkmcnt(0)" ::: "memory");
    __builtin_amdgcn_s_barrier();
    __builtin_amdgcn_sched_barrier(0);
  }

// Phase macro. Order: A-glds(p+2) ; W round ; {S1(p+1) || MFMA(p)} ;
// lgkm(0) ; vmwait<Wops> ; barrier ; swap A offsets.
// WRT: 0 none, 1 glds16@0, 2 glds16@4096, 3 glds4 x2 @8192/9216.
#define PHASE(PH, RCA, RCB, RNA, RNB, NKWA, NWBA, NKWB, NWBB, WRT, WSRCP,     \
              WDPAR)                                                          \
  {                                                                           \
    { /* A glds first (FIFO: drained by this phase's vmwait) */               \
      int sl0 = S0 + 2 * (PH) + 4;                                            \
      if (sl0 >= 676) sl0 -= 676;                                             \
      int sl1 = sl0 + 1;                                                      \
      if (sl1 >= 676) sl1 -= 676;                                             \
      const unsigned short* at0 =                                             \
          Wp + ((c2base + (size_t)(kBaseStep + sl0)) << 12);                  \
      const unsigned short* at1 =                                             \
          Wp + ((c2base + (size_t)(kBaseStep + sl1)) << 12);                  \
      unsigned short* ad = AbaseU + (aWr >> 1);                               \
      glds16(at0 + tid8, ad + widA);                                          \
      glds16(at1 + tid8, ad + 4096 + widA);                                   \
    }                                                                         \
    if ((WRT) == 1) glds16((WSRCP) + tid8, &Wbuf[(WDPAR)][0] + widA);         \
    if ((WRT) == 2)                                                           \
      glds16((WSRCP) + 4096 + tid8, &Wbuf[(WDPAR)][4096] + widA);             \
    if ((WRT) == 3) {                                                         \
      glds4((WSRCP) + 8192 + tid2, &Wbuf[(WDPAR)][8192] + wid128);            \
      glds4((WSRCP) + 9216 + tid2, &Wbuf[(WDPAR)][9216] + wid128);            \
    }                                                                         \
    __builtin_amdgcn_s_setprio(1);                                            \
    { /* S1 reads for phase PH+1 */                                           \
      const char* abA = Abase + aRd;                                          \
      const char* abB = abA + 8192;                                           \
      const char* wbA = (const char*)&Wbuf[(NWBA)][0];                        \
      const char* wbB = (const char*)&Wbuf[(NWBB)][0];                        \
      _Pragma("unroll") for (int ks = 0; ks < 2; ++ks) {                      \
        RNA[0][ks][0] = *(const bf16x8*)(abA + aoffs[0][ks]);                 \
        RNA[0][ks][1] = *(const bf16x8*)(abA + aoffs[1][ks]);                 \
        RNA[1][ks][0] = *(const bf16x8*)(abB + aoffs[0][ks]);                 \
        RNA[1][ks][1] = *(const bf16x8*)(abB + aoffs[1][ks]);                 \
        _Pragma("unroll") for (int nt = 0; nt < 2; ++nt) {                    \
          const int cA = nwl[nt] + (NKWA) + 2;                                \
          RNB[0][ks][nt] = *(const bf16x8*)(                                  \
              wbA + (ndh[nt] * 80 + cA) * 64 +                                \
              (((ks * 2 + hi2) ^ swz4(cA)) << 4));                            \
          const int cB = nwl[nt] + (NKWB) + 2;                                \
          RNB[1][ks][nt] = *(const bf16x8*)(                                  \
              wbB + (ndh[nt] * 80 + cB) * 64 +                                \
              (((ks * 2 + hi2) ^ swz4(cB)) << 4));                            \
        }                                                                     \
      }                                                                       \
    }                                                                         \
    /* MFMA(PH) on current regs */                                            \
    _Pragma("unroll") for (int s = 0; s < 2; ++s)                             \
        _Pragma("unroll") for (int ks = 0; ks < 2; ++ks) {                    \
      acc[0][0] = __builtin_amdgcn_mfma_f32_32x32x16_bf16(                    \
          RCA[s][ks][0], RCB[s][ks][0], acc[0][0], 0, 0, 0);                  \
      acc[0][1] = __builtin_amdgcn_mfma_f32_32x32x16_bf16(                    \
          RCA[s][ks][0], RCB[s][ks][1], acc[0][1], 0, 0, 0);                  \
      acc[1][0] = __builtin_amdgcn_mfma_f32_32x32x16_bf16(                    \
          RCA[s][ks][1], RCB[s][ks][0], acc[1][0], 0, 0, 0);                  \
      acc[1][1] = __builtin_amdgcn_mfma_f32_32x32x16_bf16(                    \
          RCA[s][ks][1], RCB[s][ks][1], acc[1][1], 0, 0, 0);                  \
    }                                                                         \
    __builtin_amdgcn_s_setprio(0);                                            \
    asm volatile("s_waitcnt lgkmcnt(0)" ::: "memory");                        \
    vmwait<((WRT) == 0 ? 0 : ((WRT) == 3 ? 2 : 1))>();                        \
    __builtin_amdgcn_s_barrier();                                             \
    __builtin_amdgcn_sched_barrier(0);                                        \
    { const int t_ = aWr; aWr = aRd; aRd = t_; }                              \
  }

  // 13 u-iterations x 26 phases (4 tiles, 52 local k-steps each).
  // W rounds at phases {0,1,2}, {7,8,9}, {13,14,15}, {20,21,22}:
  // last round drained >=2 phases before the tile's first read (ph 5/12/18/25).
  for (int u = 0; u < 13; ++u) {
    const int S0 = u * 52;
    const int Tb = u * 4;
    const unsigned short* wt1 = wtile((Tb + 1) % 52);
    const unsigned short* wt2 = wtile((Tb + 2) % 52);
    const unsigned short* wt3 = wtile((Tb + 3) % 52);
    const unsigned short* wt4 = wtile((Tb + 4) % 52);
    PHASE(0, rE_A, rE_B, rO_A, rO_B, 2, 0, 3, 0, 1, wt1, 1)
    PHASE(1, rO_A, rO_B, rE_A, rE_B, 4, 0, 5, 0, 2, wt1, 1)
    PHASE(2, rE_A, rE_B, rO_A, rO_B, 6, 0, 7, 0, 3, wt1, 1)
    PHASE(3, rO_A, rO_B, rE_A, rE_B, 8, 0, 9, 0, 0, wt1, 1)
    PHASE(4, rE_A, rE_B, rO_A, rO_B, 10, 0, 11, 0, 0, wt1, 1)
    PHASE(5, rO_A, rO_B, rE_A, rE_B, 12, 0, 0, 1, 0, wt1, 1)
    PHASE(6, rE_A, rE_B, rO_A, rO_B, 1, 1, 2, 1, 0, wt1, 1)
    PHASE(7, rO_A, rO_B, rE_A, rE_B, 3, 1, 4, 1, 1, wt2, 0)
    PHASE(8, rE_A, rE_B, rO_A, rO_B, 5, 1, 6, 1, 2, wt2, 0)
    PHASE(9, rO_A, rO_B, rE_A, rE_B, 7, 1, 8, 1, 3, wt2, 0)
    PHASE(10, rE_A, rE_B, rO_A, rO_B, 9, 1, 10, 1, 0, wt2, 0)
    PHASE(11, rO_A, rO_B, rE_A, rE_B, 11, 1, 12, 1, 0, wt2, 0)
    PHASE(12, rE_A, rE_B, rO_A, rO_B, 0, 0, 1, 0, 0, wt2, 0)
    PHASE(13, rO_A, rO_B, rE_A, rE_B, 2, 0, 3, 0, 1, wt3, 1)
    PHASE(14, rE_A, rE_B, rO_A, rO_B, 4, 0, 5, 0, 2, wt3, 1)
    PHASE(15, rO_A, rO_B, rE_A, rE_B, 6, 0, 7, 0, 3, wt3, 1)
    PHASE(16, rE_A, rE_B, rO_A, rO_B, 8, 0, 9, 0, 0, wt3, 1)
    PHASE(17, rO_A, rO_B, rE_A, rE_B, 10, 0, 11, 0, 0, wt3, 1)
    PHASE(18, rE_A, rE_B, rO_A, rO_B, 12, 0, 0, 1, 0, wt3, 1)
    PHASE(19, rO_A, rO_B, rE_A, rE_B, 1, 1, 2, 1, 0, wt3, 1)
    PHASE(20, rE_A, rE_B, rO_A, rO_B, 3, 1, 4, 1, 1, wt4, 0)
    PHASE(21, rO_A, rO_B, rE_A, rE_B, 5, 1, 6, 1, 2, wt4, 0)
    PHASE(22, rE_A, rE_B, rO_A, rO_B, 7, 1, 8, 1, 3, wt4, 0)
    PHASE(23, rO_A, rO_B, rE_A, rE_B, 9, 1, 10, 1, 0, wt4, 0)
    PHASE(24, rE_A, rE_B, rO_A, rO_B, 11, 1, 12, 1, 0, wt4, 0)
    PHASE(25, rO_A, rO_B, rE_A, rE_B, 0, 0, 1, 0, 0, wt4, 0)
  }
#undef PHASE

  vmwait<0>();  // drain dangling prefetches

  // ---- epilogue: plain f32 partial stores (disjoint regions, no atomics).
  // 32x32 C/D layout (m74/m101): col = lane&31, row = (r&3)+8*(r>>2)+4*(lane>>5)
#pragma unroll
  for (int mt = 0; mt < 2; ++mt) {
#pragma unroll
    for (int nt = 0; nt < 2; ++nt) {
      const int n = wn * 64 + nt * 32 + l31;
      const int hh = h0 + (n >> 6), ww = n & 63;
#pragma unroll
      for (int r = 0; r < 16; ++r) {
        const int mloc = (r & 3) + 8 * (r >> 2) + 4 * hi2;
        const int c2l = wr * 64 + mt * 32 + mloc;
        Ppart[(size_t)kHalf * 8388608 +
              ((size_t)(b * 256 + c2t * 128 + c2l)) * 4096 + hh * 64 + ww] =
            acc[mt][nt][r];
      }
    }
  }
}

// ---------------------------------------------------------------------------
// Reduce two K-half partials + BN (inference) + SiLU -> out.
// ---------------------------------------------------------------------------
__global__ __launch_bounds__(256) void reduce_bn_silu_kernel(
    const float* __restrict__ Ppart, const float* __restrict__ gamma,
    const float* __restrict__ beta, const float* __restrict__ mean,
    const float* __restrict__ var, float* __restrict__ out) {
  const int i = blockIdx.x * 256 + threadIdx.x;  // 0..524287
  const f32x4* p0 = (const f32x4*)Ppart;
  const f32x4* p1 = (const f32x4*)(Ppart + 8388608);
  f32x4* o4 = (f32x4*)out;
#pragma unroll
  for (int rr = 0; rr < 4; ++rr) {
    const int i4 = i + rr * 524288;  // 2,097,152 f32x4 total
    f32x4 v = p0[i4] + p1[i4];
    const int c2 = (i4 >> 10) & 255;
    const float inv = gamma[c2] * rsqrtf(var[c2] + EPS);
    const float sh = beta[c2] - mean[c2] * inv;
#pragma unroll
    for (int j = 0; j < 4; ++j) {
      const float y = v[j] * inv + sh;
      v[j] = y / (1.f + __expf(-y));
    }
    o4[i4] = v;
  }
}

// ---------------------------------------------------------------------------
// conv11 (R11 best, 571 us) kept as the ws>=47MB fallback path.
// ---------------------------------------------------------------------------
__global__ __launch_bounds__(256, 2) void conv11_kernel(
    const unsigned short* __restrict__ Wp, const unsigned short* __restrict__ xT,
    const float* __restrict__ gamma, const float* __restrict__ beta,
    const float* __restrict__ mean, const float* __restrict__ var,
    float* __restrict__ out) {
  __shared__ __align__(16) unsigned short Abuf[3][8192];
  __shared__ __align__(16) unsigned short Wbuf[2][5120];
  __shared__ float s_scale[128], s_shift[128];

  const int tid = threadIdx.x;
  const int bid = blockIdx.x;
  const int b = bid & 7;
  const int h0 = ((bid >> 3) & 31) * 2;
  const int c2t = bid >> 8;

  const int wid = tid >> 6, lane = tid & 63;
  const int wr = wid >> 1, wc = wid & 1;
  const int l31 = lane & 31, hi2 = lane >> 5;

  if (tid < 128) {
    const int c2 = c2t * 128 + tid;
    const float inv = gamma[c2] * rsqrtf(var[c2] + EPS);
    s_scale[tid] = inv;
    s_shift[tid] = beta[c2] - mean[c2] * inv;
  }

  int aoffs[2][2];
#pragma unroll
  for (int mt = 0; mt < 2; ++mt)
#pragma unroll
    for (int ks = 0; ks < 2; ++ks) {
      const int m = wr * 64 + mt * 32 + l31;
      aoffs[mt][ks] = m * 64 + (((ks * 2 + hi2) ^ swz4(m)) << 4);
    }
  int ndh[2], nwl[2];
#pragma unroll
  for (int nt = 0; nt < 2; ++nt) {
    const int n = wc * 64 + nt * 32 + l31;
    ndh[nt] = n >> 6;
    nwl[nt] = n & 63;
  }

  const int tid8 = tid * 8, tid2 = tid * 2;
  const int widA = wid * 512, wid128 = wid * 128;

  const size_t c2base = (size_t)c2t * 1352;
  const int bc8 = b * 8;
  const char* Abase = (const char*)&Abuf[0][0];
  unsigned short* AbaseU = &Abuf[0][0];

  auto wtile = [&](int T) -> const unsigned short* {
    const int kh = T >> 3, c1c = T & 7;
    return xT + (size_t)((bc8 + c1c) * 76 + h0 + kh) * 2560;
  };

  f32x16 acc[2][2];
#pragma unroll
  for (int i = 0; i < 2; ++i)
#pragma unroll
    for (int j = 0; j < 2; ++j)
#pragma unroll
      for (int r = 0; r < 16; ++r) acc[i][j][r] = 0.f;

  bf16x8 rE_A[2][2][2], rE_B[2][2][2], rO_A[2][2][2], rO_B[2][2][2];
  int aCur = 0, aNext = 16384, aNN = 32768;

  {
    const unsigned short* ws = wtile(0);
    glds16(ws + tid8, &Wbuf[0][0] + widA);
    glds16(ws + 2048 + tid8, &Wbuf[0][2048] + widA);
    glds4(ws + 4096 + tid2, &Wbuf[0][4096] + wid128);
    glds4(ws + 4608 + tid2, &Wbuf[0][4608] + wid128);
#pragma unroll
    for (int ph = 0; ph < 3; ++ph) {
      const unsigned short* at0 = Wp + ((c2base + 2 * ph) << 12);
      const unsigned short* at1 = Wp + ((c2base + 2 * ph + 1) << 12);
      unsigned short* ad = AbaseU + ph * 8192;
      glds16(at0 + tid8, ad + widA);
      glds16(at0 + 2048 + tid8, ad + 2048 + widA);
      glds16(at1 + tid8, ad + 4096 + widA);
      glds16(at1 + 2048 + tid8, ad + 6144 + widA);
    }
    vmwait<0>();
    __builtin_amdgcn_s_barrier();
    const char* abA = Abase;
    const char* abB = Abase + 8192;
    const char* wb0 = (const char*)&Wbuf[0][0];
#pragma unroll
    for (int ks = 0; ks < 2; ++ks) {
      rE_A[0][ks][0] = *(const bf16x8*)(abA + aoffs[0][ks]);
      rE_A[0][ks][1] = *(const bf16x8*)(abA + aoffs[1][ks]);
      rE_A[1][ks][0] = *(const bf16x8*)(abB + aoffs[0][ks]);
      rE_A[1][ks][1] = *(const bf16x8*)(abB + aoffs[1][ks]);
#pragma unroll
      for (int nt = 0; nt < 2; ++nt) {
        const int cA = nwl[nt] + 0 + 2;
        rE_B[0][ks][nt] = *(const bf16x8*)(wb0 + (ndh[nt] * 80 + cA) * 64 +
                                           (((ks * 2 + hi2) ^ swz4(cA)) << 4));
        const int cB = nwl[nt] + 1 + 2;
        rE_B[1][ks][nt] = *(const bf16x8*)(wb0 + (ndh[nt] * 80 + cB) * 64 +
                                           (((ks * 2 + hi2) ^ swz4(cB)) << 4));
      }
    }
    asm volatile("s_waitcnt lgkmcnt(0)" ::: "memory");
    __builtin_amdgcn_s_barrier();
    __builtin_amdgcn_sched_barrier(0);
  }

#define PHASE(PH, RCA, RCB, RNA, RNB, NKWA, NWBA, NKWB, NWBB, WRT, WSRCP, WDB)\
  {                                                                           \
    __builtin_amdgcn_s_setprio(1);                                            \
    {                                                                         \
      const char* abA = Abase + aNext;                                        \
      const char* abB = abA + 8192;                                           \
      const char* wbA = (const char*)&Wbuf[(NWBA)][0];                        \
      const char* wbB = (const char*)&Wbuf[(NWBB)][0];                        \
      _Pragma("unroll") for (int ks = 0; ks < 2; ++ks) {                      \
        RNA[0][ks][0] = *(const bf16x8*)(abA + aoffs[0][ks]);                 \
        RNA[0][ks][1] = *(const bf16x8*)(abA + aoffs[1][ks]);                 \
        RNA[1][ks][0] = *(const bf16x8*)(abB + aoffs[0][ks]);                 \
        RNA[1][ks][1] = *(const bf16x8*)(abB + aoffs[1][ks]);                 \
        _Pragma("unroll") for (int nt = 0; nt < 2; ++nt) {                    \
          const int cA = nwl[nt] + (NKWA) + 2;                                \
          RNB[0][ks][nt] = *(const bf16x8*)(                                  \
              wbA + (ndh[nt] * 80 + cA) * 64 +                                \
              (((ks * 2 + hi2) ^ swz4(cA)) << 4));                            \
          const int cB = nwl[nt] + (NKWB) + 2;                                \
          RNB[1][ks][nt] = *(const bf16x8*)(                                  \
              wbB + (ndh[nt] * 80 + cB) * 64 +                                \
              (((ks * 2 + hi2) ^ swz4(cB)) << 4));                            \
        }                                                                     \
      }                                                                       \
    }                                                                         \
    _Pragma("unroll") for (int s = 0; s < 2; ++s)                             \
        _Pragma("unroll") for (int ks = 0; ks < 2; ++ks) {                    \
      acc[0][0] = __builtin_amdgcn_mfma_f32_32x32x16_bf16(                    \
          RCA[s][ks][0], RCB[s][ks][0], acc[0][0], 0, 0, 0);                  \
      acc[0][1] = __builtin_amdgcn_mfma_f32_32x32x16_bf16(                    \
          RCA[s][ks][0], RCB[s][ks][1], acc[0][1], 0, 0, 0);                  \
      acc[1][0] = __builtin_amdgcn_mfma_f32_32x32x16_bf16(                    \
          RCA[s][ks][1], RCB[s][ks][0], acc[1][0], 0, 0, 0);                  \
      acc[1][1] = __builtin_amdgcn_mfma_f32_32x32x16_bf16(                    \
          RCA[s][ks][1], RCB[s][ks][1], acc[1][1], 0, 0, 0);                  \
    }                                                                         \
    __builtin_amdgcn_s_setprio(0);                                            \
    asm volatile("s_waitcnt lgkmcnt(0)" ::: "memory");                        \
    if ((WRT) == 1) glds16((WSRCP) + tid8, &Wbuf[(WDB)][0] + widA);           \
    if ((WRT) == 2)                                                           \
      glds16((WSRCP) + 2048 + tid8, &Wbuf[(WDB)][2048] + widA);               \
    if ((WRT) == 3) {                                                         \
      glds4((WSRCP) + 4096 + tid2, &Wbuf[(WDB)][4096] + wid128);              \
      glds4((WSRCP) + 4608 + tid2, &Wbuf[(WDB)][4608] + wid128);              \
    }                                                                         \
    {                                                                         \
      int sn0 = S0 + 2 * (PH) + 6;                                            \
      if (sn0 >= 1352) sn0 -= 1352;                                           \
      int sn1 = sn0 + 1;                                                      \
      if (sn1 >= 1352) sn1 -= 1352;                                           \
      const unsigned short* at0 = Wp + ((c2base + (size_t)sn0) << 12);        \
      const unsigned short* at1 = Wp + ((c2base + (size_t)sn1) << 12);        \
      unsigned short* ad = AbaseU + (aCur >> 1);                              \
      glds16(at0 + tid8, ad + widA);                                          \
      glds16(at0 + 2048 + tid8, ad + 2048 + widA);                            \
      glds16(at1 + tid8, ad + 4096 + widA);                                   \
      glds16(at1 + 2048 + tid8, ad + 6144 + widA);                            \
    }                                                                         \
    vmwait<((WRT) == 0 ? 4 : ((WRT) == 3 ? 6 : 5))>();                        \
    __builtin_amdgcn_s_barrier();                                             \
    __builtin_amdgcn_sched_barrier(0);                                        \
    { const int t_ = aCur; aCur = aNext; aNext = aNN; aNN = t_; }             \
  }

  for (int u = 0; u < 26; ++u) {
    const int S0 = u * 52;
    const int Tb = u * 4;
    const unsigned short* wt1 = wtile(Tb + 1);
    const unsigned short* wt2 = wtile(Tb + 2);
    const unsigned short* wt3 = wtile(Tb + 3);
    const unsigned short* wt4 = wtile((Tb + 4 == 104) ? 0 : Tb + 4);
    PHASE(0, rE_A, rE_B, rO_A, rO_B, 2, 0, 3, 0, 0, wt1, 1)
    PHASE(1, rO_A, rO_B, rE_A, rE_B, 4, 0, 5, 0, 1, wt1, 1)
    PHASE(2, rE_A, rE_B, rO_A, rO_B, 6, 0, 7, 0, 2, wt1, 1)
    PHASE(3, rO_A, rO_B, rE_A, rE_B, 8, 0, 9, 0, 3, wt1, 1)
    PHASE(4, rE_A, rE_B, rO_A, rO_B, 10, 0, 11, 0, 0, wt1, 1)
    PHASE(5, rO_A, rO_B, rE_A, rE_B, 12, 0, 0, 1, 0, wt1, 1)
    PHASE(6, rE_A, rE_B, rO_A, rO_B, 1, 1, 2, 1, 0, wt1, 1)
    PHASE(7, rO_A, rO_B, rE_A, rE_B, 3, 1, 4, 1, 1, wt2, 0)
    PHASE(8, rE_A, rE_B, rO_A, rO_B, 5, 1, 6, 1, 2, wt2, 0)
    PHASE(9, rO_A, rO_B, rE_A, rE_B, 7, 1, 8, 1, 3, wt2, 0)
    PHASE(10, rE_A, rE_B, rO_A, rO_B, 9, 1, 10, 1, 0, wt2, 0)
    PHASE(11, rO_A, rO_B, rE_A, rE_B, 11, 1, 12, 1, 0, wt2, 0)
    PHASE(12, rE_A, rE_B, rO_A, rO_B, 0, 0, 1, 0, 0, wt2, 0)
    PHASE(13, rO_A, rO_B, rE_A, rE_B, 2, 0, 3, 0, 0, wt3, 1)
    PHASE(14, rE_A, rE_B, rO_A, rO_B, 4, 0, 5, 0, 1, wt3, 1)
    PHASE(15, rO_A, rO_B, rE_A, rE_B, 6, 0, 7, 0, 2, wt3, 1)
    PHASE(16, rE_A, rE_B, rO_A, rO_B, 8, 0, 9, 0, 3, wt3, 1)
    PHASE(17, rO_A, rO_B, rE_A, rE_B, 10, 0, 11, 0, 0, wt3, 1)
    PHASE(18, rE_A, rE_B, rO_A, rO_B, 12, 0, 0, 1, 0, wt3, 1)
    PHASE(19, rO_A, rO_B, rE_A, rE_B, 1, 1, 2, 1, 0, wt3, 1)
    PHASE(20, rE_A, rE_B, rO_A, rO_B, 3, 1, 4, 1, 1, wt4, 0)
    PHASE(21, rO_A, rO_B, rE_A, rE_B, 5, 1, 6, 1, 2, wt4, 0)
    PHASE(22, rE_A, rE_B, rO_A, rO_B, 7, 1, 8, 1, 3, wt4, 0)
    PHASE(23, rO_A, rO_B, rE_A, rE_B, 9, 1, 10, 1, 0, wt4, 0)
    PHASE(24, rE_A, rE_B, rO_A, rO_B, 11, 1, 12, 1, 0, wt4, 0)
    PHASE(25, rO_A, rO_B, rE_A, rE_B, 0, 0, 1, 0, 0, wt4, 0)
  }
#undef PHASE

  vmwait<0>();

#pragma unroll
  for (int mt = 0; mt < 2; ++mt) {
#pragma unroll
    for (int nt = 0; nt < 2; ++nt) {
      const int n = wc * 64 + nt * 32 + l31;
      const int hh = h0 + (n >> 6), ww = n & 63;
#pragma unroll
      for (int r = 0; r < 16; ++r) {
        const int mloc = (r & 3) + 8 * (r >> 2) + 4 * hi2;
        const int c2l = wr * 64 + mt * 32 + mloc;
        const float y = acc[mt][nt][r] * s_scale[c2l] + s_shift[c2l];
        out[((size_t)(b * 256 + c2t * 128 + c2l)) * 4096 + hh * 64 + ww] =
            y / (1.f + __expf(-y));
      }
    }
  }
}

// ---------------------------------------------------------------------------
// Safety-net fallback if workspace is too small for packed buffers.
// ---------------------------------------------------------------------------
__global__ void naive_conv_kernel(
    const float* __restrict__ x, const float* __restrict__ W,
    const float* __restrict__ gamma, const float* __restrict__ beta,
    const float* __restrict__ mean, const float* __restrict__ var,
    float* __restrict__ out) {
  const int idx = blockIdx.x * 256 + threadIdx.x;
  if (idx >= 8 * 256 * 64 * 64) return;
  const int w = idx & 63, h = (idx >> 6) & 63;
  const int c2 = (idx >> 12) & 255, b = idx >> 20;
  float s = 0.f;
  for (int c1 = 0; c1 < 256; ++c1) {
    const float* xp = x + ((size_t)(b * 256 + c1) * 4096);
    const float* wp = W + ((size_t)(c2 * 256 + c1) * 169);
    for (int kh = 0; kh < 13; ++kh) {
      const int r = h + kh - 6;
      if ((unsigned)r >= 64u) continue;
      for (int kw = 0; kw < 13; ++kw) {
        const int c = w + kw - 6;
        if ((unsigned)c >= 64u) continue;
        s += xp[r * 64 + c] * wp[kh * 13 + kw];
      }
    }
  }
  const float inv = gamma[c2] * rsqrtf(var[c2] + EPS);
  const float y = s * inv + (beta[c2] - mean[c2] * inv);
  out[idx] = y / (1.f + __expf(-y));
}

extern "C" void kernel_launch(void* const* d_in, const int* in_sizes, int n_in,
                              void* d_out, int out_size, void* d_ws, size_t ws_size,
                              hipStream_t stream) {
  const float* x = (const float*)d_in[0];
  const float* W = (const float*)d_in[1];
  const float* gamma = (const float*)d_in[2];
  const float* beta = (const float*)d_in[3];
  const float* mean = (const float*)d_in[4];
  const float* var = (const float*)d_in[5];
  float* out = (float*)d_out;

  const size_t WP_BYTES = (size_t)256 * 43264 * 2;  // 22,151,168
  const size_t XT_BYTES = (size_t)12455424 * 2;     // 24,910,848
  const size_t P_BYTES = (size_t)2 * 8388608 * 4;   // 67,108,864

  if (ws_size >= WP_BYTES + XT_BYTES + P_BYTES) {
    unsigned short* Wp = (unsigned short*)d_ws;
    unsigned short* xT = (unsigned short*)((char*)d_ws + WP_BYTES);
    float* Ppart = (float*)((char*)d_ws + WP_BYTES + XT_BYTES);
    pack_w_kernel<<<256 * 13, 256, 0, stream>>>(W, Wp);
    pack_xt_kernel<<<8 * 8 * 76, 256, 0, stream>>>(x, xT);
    conv14_kernel<<<512, 512, 0, stream>>>(Wp, xT, Ppart);
    reduce_bn_silu_kernel<<<2048, 256, 0, stream>>>(Ppart, gamma, beta, mean,
                                                    var, out);
  } else if (ws_size >= WP_BYTES + XT_BYTES) {
    unsigned short* Wp = (unsigned short*)d_ws;
    unsigned short* xT = (unsigned short*)((char*)d_ws + WP_BYTES);
    pack_w_kernel<<<256 * 13, 256, 0, stream>>>(W, Wp);
    pack_xt_kernel<<<8 * 8 * 76, 256, 0, stream>>>(x, xT);
    conv11_kernel<<<512, 256, 0, stream>>>(Wp, xT, gamma, beta, mean, var, out);
  } else {
    naive_conv_kernel<<<(8 * 256 * 64 * 64 + 255) / 256, 256, 0, stream>>>(
        x, W, gamma, beta, mean, var, out);
  }
}

// Round 15
// 609.309 us; speedup vs baseline: 2.5804x; 2.5804x over previous
//
#include <hip/hip_runtime.h>
#include <stdint.h>

#define EPS 1e-5f

typedef __attribute__((ext_vector_type(8))) __bf16 bf16x8;
typedef __attribute__((ext_vector_type(16))) float f32x16;

__device__ __forceinline__ int swz4(int r) { return (r ^ (r >> 2)) & 3; }

__device__ __forceinline__ unsigned short f2bf(float f) {
  union { float f; unsigned u; } v; v.f = f;
  unsigned r = v.u + 0x7fffu + ((v.u >> 16) & 1u);
  return (unsigned short)(r >> 16);
}

__device__ __forceinline__ void glds16(const unsigned short* g, unsigned short* l) {
  __builtin_amdgcn_global_load_lds(
      (const __attribute__((address_space(1))) void*)g,
      (__attribute__((address_space(3))) void*)l, 16, 0, 0);
}
__device__ __forceinline__ void glds4(const unsigned short* g, unsigned short* l) {
  __builtin_amdgcn_global_load_lds(
      (const __attribute__((address_space(1))) void*)g,
      (__attribute__((address_space(3))) void*)l, 4, 0, 0);
}

template <int N>
__device__ __forceinline__ void vmwait() {
  asm volatile("s_waitcnt vmcnt(%0)" ::"n"(N) : "memory");
}

// ---------------------------------------------------------------------------
// Pack W [c2][c1][13][13] f32 -> bf16 per-K-step tiles = exact linear LDS
// image of the A tile (chunk swizzle baked in).
// K order: k = ((kh*8 + c1c)*13 + kw)*32 + c1i
// ---------------------------------------------------------------------------
__global__ __launch_bounds__(256) void pack_w_kernel(
    const float* __restrict__ W, unsigned short* __restrict__ Wp) {
  const int blk = blockIdx.x;  // c2*13 + kh
  const int c2 = blk / 13, kh = blk - c2 * 13;
  const int c1 = threadIdx.x;
  const int c2t = c2 >> 7, m = c2 & 127;
  const int c1c = c1 >> 5, c1i = c1 & 31;
  const float* src = W + (((size_t)(c2 * 256 + c1)) * 13 + kh) * 13;
  const int rowoff = (((c1i >> 3) ^ swz4(m)) << 3) + (c1i & 7);
#pragma unroll
  for (int kw = 0; kw < 13; ++kw) {
    const int ks = (kh * 8 + c1c) * 13 + kw;
    const size_t dst = (((size_t)c2t * 1352 + ks) * 128 + m) * 32 + rowoff;
    Wp[dst] = f2bf(src[kw]);
  }
}

// ---------------------------------------------------------------------------
// Pack x [b][c1][64][64] f32 -> xT[b][c1c][rowp 76][colp 80][c1i 32] bf16,
// zero-padded halo (rowp = row+6, colp = ic+8), chunk swizzle baked in.
// ---------------------------------------------------------------------------
__global__ __launch_bounds__(256) void pack_xt_kernel(
    const float* __restrict__ x, unsigned short* __restrict__ xT) {
  const int blk = blockIdx.x;  // (b*8 + c1c)*76 + rowp ; 4864 blocks
  const int rowp = blk % 76;
  const int bc = blk / 76;
  const int c1c = bc & 7, b = bc >> 3;
  const int row = rowp - 6;
  const bool rok = (unsigned)row < 64u;
  unsigned short* dst = xT + (size_t)blk * 2560;
  const float* srcb = x + (size_t)(b * 256 + c1c * 32) * 4096 +
                      (rok ? row * 64 : 0);
#pragma unroll
  for (int e = 0; e < 10; ++e) {
    const int idx = e * 256 + threadIdx.x;  // 0..2559
    const int colp = idx >> 5, c1i = idx & 31;
    const int ic = colp - 8;
    const float v = (rok && (unsigned)ic < 64u) ? srcb[(size_t)c1i * 4096 + ic] : 0.f;
    dst[colp * 32 + ((((c1i >> 3) ^ swz4(colp)) << 3)) + (c1i & 7)] = f2bf(v);
  }
}

// ---------------------------------------------------------------------------
// Implicit-GEMM conv + BN + SiLU.  (R11 champion: in-phase interleave,
// 1 barrier/phase, depth-3 A prefetch via rotating LDS buffers)
// Block: 256 thr (4 waves 2M x 2N), tile 128 c2 x 128 sp (2h x 64w).
// Wave tile 64x64 via 32x32x16 MFMA. Grid 512 -> 2 independent blocks/CU.
// Phase p: { MFMA(p) on regs[p&1]  ||  S1 ds_reads(p+1) -> regs[(p+1)&1] }
//          lgkm(0) ; W-round + A-glds(p+3 -> Abuf[p%3]) ; vmwait<4|5|6> ; bar.
// ---------------------------------------------------------------------------
__global__ __launch_bounds__(256, 2) void conv11_kernel(
    const unsigned short* __restrict__ Wp, const unsigned short* __restrict__ xT,
    const float* __restrict__ gamma, const float* __restrict__ beta,
    const float* __restrict__ mean, const float* __restrict__ var,
    float* __restrict__ out) {
  __shared__ __align__(16) unsigned short Abuf[3][8192];  // 3 x 16 KiB (2 steps each)
  __shared__ __align__(16) unsigned short Wbuf[2][5120];  // 2 x 10 KiB (2 rows)
  __shared__ float s_scale[128], s_shift[128];

  const int tid = threadIdx.x;
  const int bid = blockIdx.x;
  const int b = bid & 7;  // XCD-aware: blocks on XCD k share batch image k
  const int h0 = ((bid >> 3) & 31) * 2;
  const int c2t = bid >> 8;

  const int wid = tid >> 6, lane = tid & 63;
  const int wr = wid >> 1, wc = wid & 1;
  const int l31 = lane & 31, hi2 = lane >> 5;

  if (tid < 128) {
    const int c2 = c2t * 128 + tid;
    const float inv = gamma[c2] * rsqrtf(var[c2] + EPS);
    s_scale[tid] = inv;
    s_shift[tid] = beta[c2] - mean[c2] * inv;
  }

  int aoffs[2][2];
#pragma unroll
  for (int mt = 0; mt < 2; ++mt)
#pragma unroll
    for (int ks = 0; ks < 2; ++ks) {
      const int m = wr * 64 + mt * 32 + l31;
      aoffs[mt][ks] = m * 64 + (((ks * 2 + hi2) ^ swz4(m)) << 4);
    }
  int ndh[2], nwl[2];
#pragma unroll
  for (int nt = 0; nt < 2; ++nt) {
    const int n = wc * 64 + nt * 32 + l31;
    ndh[nt] = n >> 6;
    nwl[nt] = n & 63;
  }

  const int tid8 = tid * 8, tid2 = tid * 2;
  const int widA = wid * 512, wid128 = wid * 128;

  const size_t c2base = (size_t)c2t * 1352;
  const int bc8 = b * 8;
  const char* Abase = (const char*)&Abuf[0][0];
  unsigned short* AbaseU = &Abuf[0][0];

  auto wtile = [&](int T) -> const unsigned short* {
    const int kh = T >> 3, c1c = T & 7;
    return xT + (size_t)((bc8 + c1c) * 76 + h0 + kh) * 2560;
  };

  f32x16 acc[2][2];
#pragma unroll
  for (int i = 0; i < 2; ++i)
#pragma unroll
    for (int j = 0; j < 2; ++j)
#pragma unroll
      for (int r = 0; r < 16; ++r) acc[i][j][r] = 0.f;

  // double-buffered fragment registers: rE (even phases), rO (odd phases)
  bf16x8 rE_A[2][2][2], rE_B[2][2][2], rO_A[2][2][2], rO_B[2][2][2];

  // rotating byte offsets of the 3 A buffers: at phase p,
  // aCur = p%3 (glds target, data for p+3), aNext = (p+1)%3 (S1 reads now)
  int aCur = 0, aNext = 16384, aNN = 32768;

  // ---- prologue: A phases 0,1,2 (steps 0..5) -> bufs 0,1,2; W tile0 -> Wbuf0
  {
    const unsigned short* ws = wtile(0);
    glds16(ws + tid8, &Wbuf[0][0] + widA);
    glds16(ws + 2048 + tid8, &Wbuf[0][2048] + widA);
    glds4(ws + 4096 + tid2, &Wbuf[0][4096] + wid128);
    glds4(ws + 4608 + tid2, &Wbuf[0][4608] + wid128);
#pragma unroll
    for (int ph = 0; ph < 3; ++ph) {
      const unsigned short* at0 = Wp + ((c2base + 2 * ph) << 12);
      const unsigned short* at1 = Wp + ((c2base + 2 * ph + 1) << 12);
      unsigned short* ad = AbaseU + ph * 8192;
      glds16(at0 + tid8, ad + widA);
      glds16(at0 + 2048 + tid8, ad + 2048 + widA);
      glds16(at1 + tid8, ad + 4096 + widA);
      glds16(at1 + 2048 + tid8, ad + 6144 + widA);
    }
    vmwait<0>();
    __builtin_amdgcn_s_barrier();
    // preload regs for phase 0 (KWA=0,WBA=0,KWB=1,WBB=0) from Abuf[0]
    const char* abA = Abase;
    const char* abB = Abase + 8192;
    const char* wb0 = (const char*)&Wbuf[0][0];
#pragma unroll
    for (int ks = 0; ks < 2; ++ks) {
      rE_A[0][ks][0] = *(const bf16x8*)(abA + aoffs[0][ks]);
      rE_A[0][ks][1] = *(const bf16x8*)(abA + aoffs[1][ks]);
      rE_A[1][ks][0] = *(const bf16x8*)(abB + aoffs[0][ks]);
      rE_A[1][ks][1] = *(const bf16x8*)(abB + aoffs[1][ks]);
#pragma unroll
      for (int nt = 0; nt < 2; ++nt) {
        const int cA = nwl[nt] + 0 + 2;
        rE_B[0][ks][nt] = *(const bf16x8*)(wb0 + (ndh[nt] * 80 + cA) * 64 +
                                           (((ks * 2 + hi2) ^ swz4(cA)) << 4));
        const int cB = nwl[nt] + 1 + 2;
        rE_B[1][ks][nt] = *(const bf16x8*)(wb0 + (ndh[nt] * 80 + cB) * 64 +
                                           (((ks * 2 + hi2) ^ swz4(cB)) << 4));
      }
    }
    asm volatile("s_waitcnt lgkmcnt(0)" ::: "memory");
    __builtin_amdgcn_s_barrier();
    __builtin_amdgcn_sched_barrier(0);
  }

// Phase macro. RC*/current regs (MFMA), RN*/next regs (S1 reads, params N*).
#define PHASE(PH, RCA, RCB, RNA, RNB, NKWA, NWBA, NKWB, NWBB, WRT, WSRCP, WDB)\
  {                                                                           \
    __builtin_amdgcn_s_setprio(1);                                            \
    /* S1 reads for phase PH+1 (buffers ready since bar(PH-1)) */             \
    {                                                                         \
      const char* abA = Abase + aNext;                                        \
      const char* abB = abA + 8192;                                           \
      const char* wbA = (const char*)&Wbuf[(NWBA)][0];                        \
      const char* wbB = (const char*)&Wbuf[(NWBB)][0];                        \
      _Pragma("unroll") for (int ks = 0; ks < 2; ++ks) {                      \
        RNA[0][ks][0] = *(const bf16x8*)(abA + aoffs[0][ks]);                 \
        RNA[0][ks][1] = *(const bf16x8*)(abA + aoffs[1][ks]);                 \
        RNA[1][ks][0] = *(const bf16x8*)(abB + aoffs[0][ks]);                 \
        RNA[1][ks][1] = *(const bf16x8*)(abB + aoffs[1][ks]);                 \
        _Pragma("unroll") for (int nt = 0; nt < 2; ++nt) {                    \
          const int cA = nwl[nt] + (NKWA) + 2;                                \
          RNB[0][ks][nt] = *(const bf16x8*)(                                  \
              wbA + (ndh[nt] * 80 + cA) * 64 +                                \
              (((ks * 2 + hi2) ^ swz4(cA)) << 4));                            \
          const int cB = nwl[nt] + (NKWB) + 2;                                \
          RNB[1][ks][nt] = *(const bf16x8*)(                                  \
              wbB + (ndh[nt] * 80 + cB) * 64 +                                \
              (((ks * 2 + hi2) ^ swz4(cB)) << 4));                            \
        }                                                                     \
      }                                                                       \
    }                                                                         \
    /* MFMA(PH) on current regs — interleaves with the reads above */         \
    _Pragma("unroll") for (int s = 0; s < 2; ++s)                             \
        _Pragma("unroll") for (int ks = 0; ks < 2; ++ks) {                    \
      acc[0][0] = __builtin_amdgcn_mfma_f32_32x32x16_bf16(                    \
          RCA[s][ks][0], RCB[s][ks][0], acc[0][0], 0, 0, 0);                  \
      acc[0][1] = __builtin_amdgcn_mfma_f32_32x32x16_bf16(                    \
          RCA[s][ks][0], RCB[s][ks][1], acc[0][1], 0, 0, 0);                  \
      acc[1][0] = __builtin_amdgcn_mfma_f32_32x32x16_bf16(                    \
          RCA[s][ks][1], RCB[s][ks][0], acc[1][0], 0, 0, 0);                  \
      acc[1][1] = __builtin_amdgcn_mfma_f32_32x32x16_bf16(                    \
          RCA[s][ks][1], RCB[s][ks][1], acc[1][1], 0, 0, 0);                  \
    }                                                                         \
    __builtin_amdgcn_s_setprio(0);                                            \
    asm volatile("s_waitcnt lgkmcnt(0)" ::: "memory"); /* S1 done pre-bar */  \
    /* W round for a future tile */                                           \
    if ((WRT) == 1) glds16((WSRCP) + tid8, &Wbuf[(WDB)][0] + widA);           \
    if ((WRT) == 2)                                                           \
      glds16((WSRCP) + 2048 + tid8, &Wbuf[(WDB)][2048] + widA);               \
    if ((WRT) == 3) {                                                         \
      glds4((WSRCP) + 4096 + tid2, &Wbuf[(WDB)][4096] + wid128);              \
      glds4((WSRCP) + 4608 + tid2, &Wbuf[(WDB)][4608] + wid128);              \
    }                                                                         \
    /* A glds for phase PH+3 into Abuf[PH%3] (its data now lives in regs) */  \
    {                                                                         \
      int sn0 = S0 + 2 * (PH) + 6;                                            \
      if (sn0 >= 1352) sn0 -= 1352;                                           \
      int sn1 = sn0 + 1;                                                      \
      if (sn1 >= 1352) sn1 -= 1352;                                           \
      const unsigned short* at0 = Wp + ((c2base + (size_t)sn0) << 12);        \
      const unsigned short* at1 = Wp + ((c2base + (size_t)sn1) << 12);        \
      unsigned short* ad = AbaseU + (aCur >> 1);                              \
      glds16(at0 + tid8, ad + widA);                                          \
      glds16(at0 + 2048 + tid8, ad + 2048 + widA);                            \
      glds16(at1 + tid8, ad + 4096 + widA);                                   \
      glds16(at1 + 2048 + tid8, ad + 6144 + widA);                            \
    }                                                                         \
    vmwait<((WRT) == 0 ? 4 : ((WRT) == 3 ? 6 : 5))>();                        \
    __builtin_amdgcn_s_barrier();                                             \
    __builtin_amdgcn_sched_barrier(0);                                        \
    { const int t_ = aCur; aCur = aNext; aNext = aNN; aNN = t_; }             \
  }

  // 26 u-iterations x 26 phases. N-params = consume params of phase PH+1.
  for (int u = 0; u < 26; ++u) {
    const int S0 = u * 52;
    const int Tb = u * 4;
    const unsigned short* wt1 = wtile(Tb + 1);
    const unsigned short* wt2 = wtile(Tb + 2);
    const unsigned short* wt3 = wtile(Tb + 3);
    const unsigned short* wt4 = wtile((Tb + 4 == 104) ? 0 : Tb + 4);
    PHASE(0, rE_A, rE_B, rO_A, rO_B, 2, 0, 3, 0, 0, wt1, 1)
    PHASE(1, rO_A, rO_B, rE_A, rE_B, 4, 0, 5, 0, 1, wt1, 1)
    PHASE(2, rE_A, rE_B, rO_A, rO_B, 6, 0, 7, 0, 2, wt1, 1)
    PHASE(3, rO_A, rO_B, rE_A, rE_B, 8, 0, 9, 0, 3, wt1, 1)
    PHASE(4, rE_A, rE_B, rO_A, rO_B, 10, 0, 11, 0, 0, wt1, 1)
    PHASE(5, rO_A, rO_B, rE_A, rE_B, 12, 0, 0, 1, 0, wt1, 1)
    PHASE(6, rE_A, rE_B, rO_A, rO_B, 1, 1, 2, 1, 0, wt1, 1)
    PHASE(7, rO_A, rO_B, rE_A, rE_B, 3, 1, 4, 1, 1, wt2, 0)
    PHASE(8, rE_A, rE_B, rO_A, rO_B, 5, 1, 6, 1, 2, wt2, 0)
    PHASE(9, rO_A, rO_B, rE_A, rE_B, 7, 1, 8, 1, 3, wt2, 0)
    PHASE(10, rE_A, rE_B, rO_A, rO_B, 9, 1, 10, 1, 0, wt2, 0)
    PHASE(11, rO_A, rO_B, rE_A, rE_B, 11, 1, 12, 1, 0, wt2, 0)
    PHASE(12, rE_A, rE_B, rO_A, rO_B, 0, 0, 1, 0, 0, wt2, 0)
    PHASE(13, rO_A, rO_B, rE_A, rE_B, 2, 0, 3, 0, 0, wt3, 1)
    PHASE(14, rE_A, rE_B, rO_A, rO_B, 4, 0, 5, 0, 1, wt3, 1)
    PHASE(15, rO_A, rO_B, rE_A, rE_B, 6, 0, 7, 0, 2, wt3, 1)
    PHASE(16, rE_A, rE_B, rO_A, rO_B, 8, 0, 9, 0, 3, wt3, 1)
    PHASE(17, rO_A, rO_B, rE_A, rE_B, 10, 0, 11, 0, 0, wt3, 1)
    PHASE(18, rE_A, rE_B, rO_A, rO_B, 12, 0, 0, 1, 0, wt3, 1)
    PHASE(19, rO_A, rO_B, rE_A, rE_B, 1, 1, 2, 1, 0, wt3, 1)
    PHASE(20, rE_A, rE_B, rO_A, rO_B, 3, 1, 4, 1, 1, wt4, 0)
    PHASE(21, rO_A, rO_B, rE_A, rE_B, 5, 1, 6, 1, 2, wt4, 0)
    PHASE(22, rE_A, rE_B, rO_A, rO_B, 7, 1, 8, 1, 3, wt4, 0)
    PHASE(23, rO_A, rO_B, rE_A, rE_B, 9, 1, 10, 1, 0, wt4, 0)
    PHASE(24, rE_A, rE_B, rO_A, rO_B, 11, 1, 12, 1, 0, wt4, 0)
    PHASE(25, rO_A, rO_B, rE_A, rE_B, 0, 0, 1, 0, 0, wt4, 0)
  }
#undef PHASE

  vmwait<0>();  // drain dangling prefetches

  // ---- epilogue: BN + SiLU.
  // 32x32 C/D layout (m74/m101): col = lane&31, row = (r&3)+8*(r>>2)+4*(lane>>5)
#pragma unroll
  for (int mt = 0; mt < 2; ++mt) {
#pragma unroll
    for (int nt = 0; nt < 2; ++nt) {
      const int n = wc * 64 + nt * 32 + l31;
      const int hh = h0 + (n >> 6), ww = n & 63;
#pragma unroll
      for (int r = 0; r < 16; ++r) {
        const int mloc = (r & 3) + 8 * (r >> 2) + 4 * hi2;
        const int c2l = wr * 64 + mt * 32 + mloc;
        const float y = acc[mt][nt][r] * s_scale[c2l] + s_shift[c2l];
        out[((size_t)(b * 256 + c2t * 128 + c2l)) * 4096 + hh * 64 + ww] =
            y / (1.f + __expf(-y));
      }
    }
  }
}

// ---------------------------------------------------------------------------
// Safety-net fallback if workspace is too small for packed buffers.
// ---------------------------------------------------------------------------
__global__ void naive_conv_kernel(
    const float* __restrict__ x, const float* __restrict__ W,
    const float* __restrict__ gamma, const float* __restrict__ beta,
    const float* __restrict__ mean, const float* __restrict__ var,
    float* __restrict__ out) {
  const int idx = blockIdx.x * 256 + threadIdx.x;
  if (idx >= 8 * 256 * 64 * 64) return;
  const int w = idx & 63, h = (idx >> 6) & 63;
  const int c2 = (idx >> 12) & 255, b = idx >> 20;
  float s = 0.f;
  for (int c1 = 0; c1 < 256; ++c1) {
    const float* xp = x + ((size_t)(b * 256 + c1) * 4096);
    const float* wp = W + ((size_t)(c2 * 256 + c1) * 169);
    for (int kh = 0; kh < 13; ++kh) {
      const int r = h + kh - 6;
      if ((unsigned)r >= 64u) continue;
      for (int kw = 0; kw < 13; ++kw) {
        const int c = w + kw - 6;
        if ((unsigned)c >= 64u) continue;
        s += xp[r * 64 + c] * wp[kh * 13 + kw];
      }
    }
  }
  const float inv = gamma[c2] * rsqrtf(var[c2] + EPS);
  const float y = s * inv + (beta[c2] - mean[c2] * inv);
  out[idx] = y / (1.f + __expf(-y));
}

extern "C" void kernel_launch(void* const* d_in, const int* in_sizes, int n_in,
                              void* d_out, int out_size, void* d_ws, size_t ws_size,
                              hipStream_t stream) {
  const float* x = (const float*)d_in[0];
  const float* W = (const float*)d_in[1];
  const float* gamma = (const float*)d_in[2];
  const float* beta = (const float*)d_in[3];
  const float* mean = (const float*)d_in[4];
  const float* var = (const float*)d_in[5];
  float* out = (float*)d_out;

  const size_t WP_BYTES = (size_t)256 * 43264 * 2;  // 22,151,168
  const size_t XT_BYTES = (size_t)12455424 * 2;     // 24,910,848

  if (ws_size >= WP_BYTES + XT_BYTES) {
    unsigned short* Wp = (unsigned short*)d_ws;
    unsigned short* xT = (unsigned short*)((char*)d_ws + WP_BYTES);
    pack_w_kernel<<<256 * 13, 256, 0, stream>>>(W, Wp);
    pack_xt_kernel<<<8 * 8 * 76, 256, 0, stream>>>(x, xT);
    conv11_kernel<<<512, 256, 0, stream>>>(Wp, xT, gamma, beta, mean, var, out);
  } else {
    naive_conv_kernel<<<(8 * 256 * 64 * 64 + 255) / 256, 256, 0, stream>>>(
        x, W, gamma, beta, mean, var, out);
  }
}